// Round 9
// baseline (181.026 us; speedup 1.0000x reference)
//
#include <hip/hip_runtime.h>
#include <hip/hip_bf16.h>
#include <cstdint>
#include <cstddef>

// Problem constants: B=1, L=4096, DM=1024, NH=16, DH=64, w=512, C=8
#define L_ 4096
#define DM_ 1024
#define NH_ 16
#define DH_ 64
#define W_ 512
#define C_ 8
#define W3_ 1536
#define NROWS_ 65536

typedef __attribute__((ext_vector_type(8))) short short8;
typedef __attribute__((ext_vector_type(4))) float f32x4;

__device__ __forceinline__ void async16(const void* g, void* l) {
    __builtin_amdgcn_global_load_lds(
        (const __attribute__((address_space(1))) unsigned int*)g,
        (__attribute__((address_space(3))) unsigned int*)l, 16, 0, 0);
}

#if __has_builtin(__builtin_amdgcn_exp2f)
#define FEXP2(x) __builtin_amdgcn_exp2f(x)
#else
#define FEXP2(x) exp2f(x)
#endif

// Counted-wait + raw-barrier helpers (T4).
#define WAITV(N) asm volatile("s_waitcnt vmcnt(" #N ")" ::: "memory")
#define WAITL0() asm volatile("s_waitcnt lgkmcnt(0)" ::: "memory")
#define BARRIER() do { __builtin_amdgcn_s_barrier(); \
                       __builtin_amdgcn_sched_barrier(0); } while (0)

__device__ __forceinline__ int nanhit(unsigned u) {
    return (((u & 0x7F80u) == 0x7F80u) | (((u >> 16) & 0x7F80u) == 0x7F80u));
}

__device__ __forceinline__ float ldf(const void* X, size_t i, int f32) {
    return f32 ? ((const float*)X)[i] : __bfloat162float(((const __hip_bfloat16*)X)[i]);
}

// ---------------------------------------------------------------------------
// Megaprep (one dispatch, detect folded in) — unchanged from R4-R8.
// ---------------------------------------------------------------------------
__global__ __launch_bounds__(256) void megaprep(const void* __restrict__ q,
                                                const void* __restrict__ kv,
                                                const void* __restrict__ Wq,
                                                const void* __restrict__ Wkv,
                                                const void* __restrict__ Wc,
                                                __hip_bfloat16* __restrict__ qbuf,
                                                __hip_bfloat16* __restrict__ WqT,
                                                __hip_bfloat16* __restrict__ WkvT,
                                                __hip_bfloat16* __restrict__ WcT,
                                                __hip_bfloat16* __restrict__ kvcomb,
                                                int* __restrict__ flag) {
    __shared__ float t[64][65];
    __shared__ int sflag;
    const int b = blockIdx.x;
    const int tid = threadIdx.x;

    if (tid == 0) sflag = 0;
    __syncthreads();
    {
        int hit = 0;
#pragma unroll
        for (int r = 0; r < 4; ++r) {
            uint4 v = ((const uint4*)q)[tid + 256 * r];
            hit |= nanhit(v.x) | nanhit(v.y) | nanhit(v.z) | nanhit(v.w);
        }
        if (__any(hit)) { if ((tid & 63) == 0) atomicOr(&sflag, 1); }
    }
    __syncthreads();
    const int f32 = sflag;
    if (b == 0 && tid == 0) flag[0] = f32;

    if (b < 4096) {
        int i = (b * 256 + tid) * 4;
        if (f32) {
            float4 v = *(const float4*)((const float*)q + i);
            __hip_bfloat162 tmp[2] = {__float22bfloat162_rn({v.x, v.y}),
                                      __float22bfloat162_rn({v.z, v.w})};
            *(short4*)((short*)qbuf + i) = *(const short4*)tmp;
        } else {
            *(short4*)((short*)qbuf + i) = *(const short4*)((const short*)q + i);
        }
    } else if (b < 4640) {
        const void* W;
        __hip_bfloat16* WT;
        int K = 1024, N, n0, k0;
        if (b < 4352) {
            int bx = b - 4096; W = Wq; WT = WqT; N = 1024;
            n0 = (bx & 15) * 64; k0 = (bx >> 4) * 64;
        } else if (b < 4608) {
            int bx = b - 4352; W = Wc; WT = WcT; N = 1024;
            n0 = (bx & 15) * 64; k0 = (bx >> 4) * 64;
        } else {
            int bx = b - 4608; W = Wkv; WT = WkvT; N = 128;
            n0 = (bx & 1) * 64; k0 = (bx >> 1) * 64;
        }
        const int tx = tid & 63;
        const int ty = tid >> 6;
#pragma unroll
        for (int r = 0; r < 16; ++r) {
            int k = ty + r * 4;
            t[k][tx] = ldf(W, (size_t)(k0 + k) * N + n0 + tx, f32);
        }
        __syncthreads();
#pragma unroll
        for (int r = 0; r < 16; ++r) {
            int n = ty + r * 4;
            WT[(size_t)(n0 + n) * K + k0 + tx] = __float2bfloat16(t[tx][n]);
        }
    } else {
        int y = b - 4640;           // 0..511
        int c = tid * 4;
        float s0 = 0, s1 = 0, s2 = 0, s3 = 0;
        float f0 = 0, f1 = 0, f2 = 0, f3 = 0;
        float l0 = 0, l1 = 0, l2 = 0, l3 = 0;
#pragma unroll
        for (int z = 0; z < C_; ++z) {
            size_t base = (size_t)(z * W_ + y) * 1024 + c;
            float a0, a1, a2, a3;
            if (f32) {
                float4 v = *(const float4*)((const float*)kv + base);
                a0 = v.x; a1 = v.y; a2 = v.z; a3 = v.w;
            } else {
                short4 v = *(const short4*)((const short*)kv + base);
                a0 = __bfloat162float(*(__hip_bfloat16*)&v.x);
                a1 = __bfloat162float(*(__hip_bfloat16*)&v.y);
                a2 = __bfloat162float(*(__hip_bfloat16*)&v.z);
                a3 = __bfloat162float(*(__hip_bfloat16*)&v.w);
            }
            s0 += a0; s1 += a1; s2 += a2; s3 += a3;
            if (z == 0) { f0 = a0; f1 = a1; f2 = a2; f3 = a3; }
            if (z == C_ - 1) { l0 = a0; l1 = a1; l2 = a2; l3 = a3; }
        }
        auto store = [&](int row, float x0, float x1, float x2, float x3) {
            __hip_bfloat162 tmp[2] = {__float22bfloat162_rn({x0, x1}),
                                      __float22bfloat162_rn({x2, x3})};
            *(short4*)((short*)kvcomb + (size_t)row * 1024 + c) = *(const short4*)tmp;
        };
        store(y,        s0 - l0, s1 - l1, s2 - l2, s3 - l3);
        store(512 + y,  s0, s1, s2, s3);
        store(1024 + y, s0 - f0, s1 - f1, s2 - f2, s3 - f3);
    }
}

// ---------------------------------------------------------------------------
// MFMA GEMM — Round 9: 128x128 tile (m93 ladder step: 64-wide -> 128² was
// +51%). BK=64, 4 waves in a 2x2 grid, each owning a 64x64 sub-tile
// (acc[4][4], 32 MFMA/K-step/wave — 2x compute per barrier pair vs R8's
// 128x64). Staging 8 x async16/thread/K-step, counted vmcnt(8), LDS 64KB
// dbuf. Counted-vmcnt 2-phase loop kept from R6.
// cMode: 0 = follow flag, 1 = fp32, 2 = bf16, 3 = swizzled K/V epilogue.
// ntiles = N/128. Dual-problem dispatch as before.
// ---------------------------------------------------------------------------
struct GemmP {
    const __hip_bfloat16* A;
    const __hip_bfloat16* BT;
    void* C;
    int M, N, K;
    float alpha;
    int cMode;
    int ntiles;   // N / 128
    int swz;
    int nblocks;
    void* C2;
};

__global__ __launch_bounds__(256) void gemm_bt_mfma(GemmP p0, GemmP p1,
                                                    const int* __restrict__ flag) {
    __shared__ __hip_bfloat16 Asl[2][2][128 * 32];   // [buf][kc] 8KB each
    __shared__ __hip_bfloat16 Bsl[2][2][128 * 32];

    GemmP p;
    int bid;
    if ((int)blockIdx.x < p0.nblocks) { p = p0; bid = blockIdx.x; }
    else { p = p1; bid = (int)blockIdx.x - p0.nblocks; }

    int mt, nt;
    if (!p.swz) { mt = bid / p.ntiles; nt = bid % p.ntiles; }
    else {
        int g = bid / (8 * p.ntiles);
        int rem = bid % (8 * p.ntiles);
        mt = g * 8 + (rem & 7);
        nt = rem >> 3;
    }
    const int m0 = mt * 128;
    const int n0 = nt * 128;
    const int K = p.K;
    const int N = p.N;

    const int tid = threadIdx.x;
    const int lane = tid & 63;
    const int wv = tid >> 6;
    const int wm = wv >> 1;          // 2x2 wave grid over 128x128
    const int wn = wv & 1;
    const int col = lane & 15;
    const int quad = lane >> 4;

    const int srow = tid >> 2;       // 0..63 staging row within a 64-row round
    const int scol = (tid & 3) * 8;  // 0/8/16/24 staging col (bf16 elems)
    const __hip_bfloat16* Ag = p.A + (size_t)m0 * K;
    const __hip_bfloat16* Bg = p.BT + (size_t)n0 * K;

    f32x4 acc[4][4] = {};

    auto STAGE = [&](int bf, int k0) {   // 8 x async16 per thread
#pragma unroll
        for (int h = 0; h < 2; ++h) {
            int row = h * 64 + srow;
#pragma unroll
            for (int kc = 0; kc < 2; ++kc) {
                async16(Ag + (size_t)row * K + k0 + kc * 32 + scol,
                        &Asl[bf][kc][row * 32 + scol]);
                async16(Bg + (size_t)row * K + k0 + kc * 32 + scol,
                        &Bsl[bf][kc][row * 32 + scol]);
            }
        }
    };

    const int NT = K >> 6;
    STAGE(0, 0);                 // first iter's vmcnt(8) covers this

    int bf = 0;
    for (int t = 0; t < NT; ++t) {
        if (t + 1 < NT) {
            STAGE(bf ^ 1, (t + 1) << 6);   // 8 in flight across the barrier
            WAITV(8);                      // cur tile landed (mine)
        } else {
            WAITV(0);                      // peeled tail: drain
        }
        BARRIER();                          // all waves' cur loads landed

#pragma unroll
        for (int kc = 0; kc < 2; ++kc) {
            short8 af[4], bfr[4];
#pragma unroll
            for (int i = 0; i < 4; ++i)
                af[i] = *(const short8*)(&Asl[bf][kc][(wm * 64 + i * 16 + col) * 32 + quad * 8]);
#pragma unroll
            for (int j = 0; j < 4; ++j)
                bfr[j] = *(const short8*)(&Bsl[bf][kc][(wn * 64 + j * 16 + col) * 32 + quad * 8]);
#pragma unroll
            for (int am = 0; am < 4; ++am)
#pragma unroll
                for (int bn = 0; bn < 4; ++bn)
                    acc[am][bn] = __builtin_amdgcn_mfma_f32_16x16x32_bf16(af[am], bfr[bn], acc[am][bn], 0, 0, 0);
        }
        WAITL0();                           // my ds_reads of buf[bf] retired
        BARRIER();                          // safe to overwrite buf[bf] next iter
        bf ^= 1;
    }

    if (p.cMode == 3) {
        // K/V epilogue: scatter bf16 into swizzled tile images.
#pragma unroll
        for (int am = 0; am < 4; ++am)
#pragma unroll
            for (int bn = 0; bn < 4; ++bn)
#pragma unroll
                for (int r = 0; r < 4; ++r) {
                    int key = m0 + wm * 64 + am * 16 + quad * 4 + r;
                    int c = n0 + wn * 64 + bn * 16 + col;
                    float v = acc[am][bn][r];
                    int g = key >> 6, kr = key & 63;
                    if (c < 64) {
                        int byt = g * 8192 + kr * 128 +
                                  ((((c >> 3) ^ (kr & 7)) << 4)) + ((c & 7) << 1);
                        *(__hip_bfloat16*)((char*)p.C + byt) = __float2bfloat16(v);
                    } else {
                        int d = c - 64;
                        int pp = ((kr & 15) << 2) | (kr >> 4);
                        int byt = g * 8192 + d * 128 +
                                  ((((pp >> 3) ^ (d & 7)) << 4)) + ((pp & 7) << 1);
                        *(__hip_bfloat16*)((char*)p.C2 + byt) = __float2bfloat16(v);
                    }
                }
        return;
    }

    int cF = (p.cMode == 1) ? 1 : ((p.cMode == 2) ? 0 : flag[0]);
#pragma unroll
    for (int am = 0; am < 4; ++am)
#pragma unroll
        for (int bn = 0; bn < 4; ++bn)
#pragma unroll
            for (int r = 0; r < 4; ++r) {
                size_t ci = (size_t)(m0 + wm * 64 + am * 16 + quad * 4 + r) * N
                            + n0 + wn * 64 + bn * 16 + col;
                float v = acc[am][bn][r] * p.alpha;
                if (cF) ((float*)p.C)[ci] = v;
                else ((__hip_bfloat16*)p.C)[ci] = __float2bfloat16(v);
            }
}

// ---------------------------------------------------------------------------
// Flash MFMA attention — unchanged from Round 8 (43.8 µs): 128-row blocks,
// 32 q-rows/wave, single-barrier 3-buffer rotation, swizzled K/V staging,
// wave-private P LDS, T5 setprio. LDS 67.6KB, 2 blk/CU.
// ---------------------------------------------------------------------------
#define PSTRIDE 72
__global__ __launch_bounds__(256, 2) void attn_kernel(const __hip_bfloat16* __restrict__ qb,
                                                      const __hip_bfloat16* __restrict__ Kb,
                                                      const __hip_bfloat16* __restrict__ Vt,
                                                      __hip_bfloat16* __restrict__ ctx) {
    __shared__ __align__(16) __hip_bfloat16 Kbuf[3][4096];   // 3 x 8KB rotation
    __shared__ __align__(16) __hip_bfloat16 Vbuf[3][4096];   // 3 x 8KB rotation
    __shared__ __align__(16) __hip_bfloat16 psm[4][32 * PSTRIDE];

    const int tid = threadIdx.x;
    const int lane = tid & 63;
    const int wv = tid >> 6;
    const int m0 = blockIdx.x * 128 + wv * 32;   // this wave's 32 q-rows
    const int col = lane & 15;
    const int quad = lane >> 4;
    __hip_bfloat16* pw = psm[wv];

    const char* Kg = (const char*)Kb;
    const char* Vg = (const char*)Vt;
    const int so = tid * 16;                    // staging byte offset (linear)

    const int off0 = ((quad ^ (col & 7)) << 4);
    const int off1 = (((quad + 4) ^ (col & 7)) << 4);

    short8 qf[2][2];
#pragma unroll
    for (int rg = 0; rg < 2; ++rg) {
        const __hip_bfloat16* qp = qb + (size_t)(m0 + rg * 16 + col) * 64 + quad * 8;
        qf[rg][0] = *(const short8*)(qp);
        qf[rg][1] = *(const short8*)(qp + 32);
    }

    f32x4 O[2][4] = {};
    float lrow[2][4] = {};

    // Prologue: stage tile 0 into rotation slot 0.
    async16(Kg + so, (char*)Kbuf[0] + so);
    async16(Kg + 4096 + so, (char*)Kbuf[0] + 4096 + so);
    async16(Vg + so, (char*)Vbuf[0] + so);
    async16(Vg + 4096 + so, (char*)Vbuf[0] + 4096 + so);

    int cur = 0;
    for (int t = 0; t < 24; ++t) {
        WAITV(0);            // tile t's loads (issued last iter) landed; ~free
        BARRIER();           // all waves' tile-t loads landed; iter t-2 done

        if (t < 23) {        // stage tile t+1 into slot (cur+1)%3 (read at t-2)
            const int nxt = (cur == 2) ? 0 : cur + 1;
            const char* ks = Kg + (size_t)(t + 1) * 8192;
            const char* vs = Vg + (size_t)(t + 1) * 8192;
            char* kd = (char*)Kbuf[nxt];
            char* vd = (char*)Vbuf[nxt];
            async16(ks + so, kd + so);
            async16(ks + 4096 + so, kd + 4096 + so);
            async16(vs + so, vd + so);
            async16(vs + 4096 + so, vd + 4096 + so);
        }

        const char* Kc = (const char*)Kbuf[cur];
        const char* Vc = (const char*)Vbuf[cur];

        short8 kb0[4], kb1[4];
#pragma unroll
        for (int f = 0; f < 4; ++f) {
            const int rb = (f * 16 + col) * 128;
            kb0[f] = *(const short8*)(Kc + rb + off0);
            kb1[f] = *(const short8*)(Kc + rb + off1);
        }

#pragma unroll
        for (int rg = 0; rg < 2; ++rg) {
            f32x4 S[4];
            __builtin_amdgcn_s_setprio(1);
#pragma unroll
            for (int f = 0; f < 4; ++f) {
                f32x4 s = {};
                s = __builtin_amdgcn_mfma_f32_16x16x32_bf16(qf[rg][0], kb0[f], s, 0, 0, 0);
                s = __builtin_amdgcn_mfma_f32_16x16x32_bf16(qf[rg][1], kb1[f], s, 0, 0, 0);
                S[f] = s;
            }
            __builtin_amdgcn_s_setprio(0);
#pragma unroll
            for (int f = 0; f < 4; ++f)
#pragma unroll
                for (int r = 0; r < 4; ++r) S[f][r] = FEXP2(S[f][r]);
#pragma unroll
            for (int r = 0; r < 4; ++r)
                lrow[rg][r] += (S[0][r] + S[1][r]) + (S[2][r] + S[3][r]);
#pragma unroll
            for (int r = 0; r < 4; ++r) {
                __hip_bfloat162 p01 = __float22bfloat162_rn({S[0][r], S[1][r]});
                __hip_bfloat162 p23 = __float22bfloat162_rn({S[2][r], S[3][r]});
                short4 t4;
                *(__hip_bfloat162*)(&t4.x) = p01;
                *(__hip_bfloat162*)(&t4.z) = p23;
                *(short4*)(pw + (rg * 16 + quad * 4 + r) * PSTRIDE + col * 4) = t4;
            }
        }

        short8 vb0[4], vb1[4];
#pragma unroll
        for (int f = 0; f < 4; ++f) {
            const int rb = (f * 16 + col) * 128;
            vb0[f] = *(const short8*)(Vc + rb + off0);
            vb1[f] = *(const short8*)(Vc + rb + off1);
        }

#pragma unroll
        for (int rg = 0; rg < 2; ++rg) {
            short8 a0 = *(const short8*)(pw + (rg * 16 + col) * PSTRIDE + quad * 8);
            short8 a1 = *(const short8*)(pw + (rg * 16 + col) * PSTRIDE + 32 + quad * 8);
            __builtin_amdgcn_s_setprio(1);
#pragma unroll
            for (int f = 0; f < 4; ++f) {
                O[rg][f] = __builtin_amdgcn_mfma_f32_16x16x32_bf16(a0, vb0[f], O[rg][f], 0, 0, 0);
                O[rg][f] = __builtin_amdgcn_mfma_f32_16x16x32_bf16(a1, vb1[f], O[rg][f], 0, 0, 0);
            }
            __builtin_amdgcn_s_setprio(0);
        }

        cur = (cur == 2) ? 0 : cur + 1;
    }

#pragma unroll
    for (int msk = 1; msk <= 8; msk <<= 1)
#pragma unroll
        for (int rg = 0; rg < 2; ++rg)
#pragma unroll
            for (int r = 0; r < 4; ++r) lrow[rg][r] += __shfl_xor(lrow[rg][r], msk, 64);

#pragma unroll
    for (int rg = 0; rg < 2; ++rg)
#pragma unroll
        for (int r = 0; r < 4; ++r) {
            float inv = 1.f / lrow[rg][r];
#pragma unroll
            for (int f = 0; f < 4; ++f)
                ctx[(size_t)(m0 + rg * 16 + quad * 4 + r) * 64 + f * 16 + col] =
                    __float2bfloat16(O[rg][f][r] * inv);
        }
}

// ---------------------------------------------------------------------------
// Launch: 4 dispatches — megaprep -> merged GEMM (qb + K/V direct) -> attn
// -> out GEMM. GEMM grids now 128x128-tiled: qb 256 (+12 rider), out 256.
// ---------------------------------------------------------------------------
extern "C" void kernel_launch(void* const* d_in, const int* in_sizes, int n_in,
                              void* d_out, int out_size, void* d_ws, size_t ws_size,
                              hipStream_t stream) {
    const void* q   = d_in[0];
    const void* kv  = d_in[1];
    const void* Wq  = d_in[2];
    const void* Wkv = d_in[3];
    const void* Wc  = d_in[4];

    char* ws = (char*)d_ws;
    size_t off = 0;
    int* flag = (int*)(ws + off); off += 1024;
    __hip_bfloat16* qbuf   = (__hip_bfloat16*)(ws + off); off += (size_t)L_ * DM_ * 2;     // 8 MB
    __hip_bfloat16* WqT    = (__hip_bfloat16*)(ws + off); off += (size_t)DM_ * DM_ * 2;    // 2 MB
    __hip_bfloat16* WkvT   = (__hip_bfloat16*)(ws + off); off += (size_t)128 * DM_ * 2;    // 256 KB
    __hip_bfloat16* WcT    = (__hip_bfloat16*)(ws + off); off += (size_t)DM_ * DM_ * 2;    // 2 MB
    __hip_bfloat16* qb     = (__hip_bfloat16*)(ws + off); off += (size_t)L_ * DM_ * 2;     // 8 MB
    __hip_bfloat16* kvcomb = (__hip_bfloat16*)(ws + off); off += (size_t)1536 * 1024 * 2;  // 3 MB
    __hip_bfloat16* Kb     = (__hip_bfloat16*)(ws + off); off += (size_t)W3_ * 64 * 2;     // 192 KB
    __hip_bfloat16* Vt     = (__hip_bfloat16*)(ws + off); off += (size_t)64 * W3_ * 2;     // 192 KB
    __hip_bfloat16* ctxb   = (__hip_bfloat16*)(ws + off);                                  // 8 MB

    megaprep<<<5152, 256, 0, stream>>>(q, kv, Wq, Wkv, Wc,
                                       qbuf, WqT, WkvT, WcT, kvcomb, flag);

    // Merged dispatch: qb = (q @ Wq) * (1/8)*log2(e), bf16 (256 blocks) PLUS
    // {Kb,Vt} = kvcomb @ Wkv with swizzled K/V epilogue (12 blocks).
    {
        GemmP pq{qbuf, WqT, (void*)qb, L_, DM_, DM_,
                 0.125f * 1.44269504f, 2, 8, 1, 256, nullptr};
        GemmP pk{kvcomb, WkvT, (void*)Kb, 1536, 128, DM_,
                 1.0f, 3, 1, 0, 12, (void*)Vt};
        gemm_bt_mfma<<<268, 256, 0, stream>>>(pq, pk, flag);
    }
    attn_kernel<<<dim3(NROWS_ / 128), 256, 0, stream>>>(qb, Kb, Vt, ctxb);
    // out = ctx @ Wc, dtype per flag
    {
        GemmP pc{ctxb, WcT, d_out, L_, DM_, DM_, 1.0f, 0, 8, 1, 256, nullptr};
        GemmP pnull{};
        pnull.nblocks = 0;
        gemm_bt_mfma<<<256, 256, 0, stream>>>(pc, pnull, flag);
    }
}

// Round 11
// 169.749 us; speedup vs baseline: 1.0664x; 1.0664x over previous
//
#include <hip/hip_runtime.h>
#include <hip/hip_bf16.h>
#include <cstdint>
#include <cstddef>

// Problem constants: B=1, L=4096, DM=1024, NH=16, DH=64, w=512, C=8
#define L_ 4096
#define DM_ 1024
#define NH_ 16
#define DH_ 64
#define W_ 512
#define C_ 8
#define W3_ 1536
#define NROWS_ 65536

typedef __attribute__((ext_vector_type(8))) short short8;
typedef __attribute__((ext_vector_type(4))) float f32x4;

__device__ __forceinline__ void async16(const void* g, void* l) {
    __builtin_amdgcn_global_load_lds(
        (const __attribute__((address_space(1))) unsigned int*)g,
        (__attribute__((address_space(3))) unsigned int*)l, 16, 0, 0);
}

#if __has_builtin(__builtin_amdgcn_exp2f)
#define FEXP2(x) __builtin_amdgcn_exp2f(x)
#else
#define FEXP2(x) exp2f(x)
#endif

// Counted-wait + raw-barrier helpers (T4).
#define WAITV(N) asm volatile("s_waitcnt vmcnt(" #N ")" ::: "memory")
#define WAITL0() asm volatile("s_waitcnt lgkmcnt(0)" ::: "memory")
#define BARRIER() do { __builtin_amdgcn_s_barrier(); \
                       __builtin_amdgcn_sched_barrier(0); } while (0)

__device__ __forceinline__ int nanhit(unsigned u) {
    return (((u & 0x7F80u) == 0x7F80u) | (((u >> 16) & 0x7F80u) == 0x7F80u));
}

__device__ __forceinline__ float ldf(const void* X, size_t i, int f32) {
    return f32 ? ((const float*)X)[i] : __bfloat162float(((const __hip_bfloat16*)X)[i]);
}

// ---------------------------------------------------------------------------
// Megaprep (one dispatch, detect folded in) — unchanged from R4-R8.
// ---------------------------------------------------------------------------
__global__ __launch_bounds__(256) void megaprep(const void* __restrict__ q,
                                                const void* __restrict__ kv,
                                                const void* __restrict__ Wq,
                                                const void* __restrict__ Wkv,
                                                const void* __restrict__ Wc,
                                                __hip_bfloat16* __restrict__ qbuf,
                                                __hip_bfloat16* __restrict__ WqT,
                                                __hip_bfloat16* __restrict__ WkvT,
                                                __hip_bfloat16* __restrict__ WcT,
                                                __hip_bfloat16* __restrict__ kvcomb,
                                                int* __restrict__ flag) {
    __shared__ float t[64][65];
    __shared__ int sflag;
    const int b = blockIdx.x;
    const int tid = threadIdx.x;

    if (tid == 0) sflag = 0;
    __syncthreads();
    {
        int hit = 0;
#pragma unroll
        for (int r = 0; r < 4; ++r) {
            uint4 v = ((const uint4*)q)[tid + 256 * r];
            hit |= nanhit(v.x) | nanhit(v.y) | nanhit(v.z) | nanhit(v.w);
        }
        if (__any(hit)) { if ((tid & 63) == 0) atomicOr(&sflag, 1); }
    }
    __syncthreads();
    const int f32 = sflag;
    if (b == 0 && tid == 0) flag[0] = f32;

    if (b < 4096) {
        int i = (b * 256 + tid) * 4;
        if (f32) {
            float4 v = *(const float4*)((const float*)q + i);
            __hip_bfloat162 tmp[2] = {__float22bfloat162_rn({v.x, v.y}),
                                      __float22bfloat162_rn({v.z, v.w})};
            *(short4*)((short*)qbuf + i) = *(const short4*)tmp;
        } else {
            *(short4*)((short*)qbuf + i) = *(const short4*)((const short*)q + i);
        }
    } else if (b < 4640) {
        const void* W;
        __hip_bfloat16* WT;
        int K = 1024, N, n0, k0;
        if (b < 4352) {
            int bx = b - 4096; W = Wq; WT = WqT; N = 1024;
            n0 = (bx & 15) * 64; k0 = (bx >> 4) * 64;
        } else if (b < 4608) {
            int bx = b - 4352; W = Wc; WT = WcT; N = 1024;
            n0 = (bx & 15) * 64; k0 = (bx >> 4) * 64;
        } else {
            int bx = b - 4608; W = Wkv; WT = WkvT; N = 128;
            n0 = (bx & 1) * 64; k0 = (bx >> 1) * 64;
        }
        const int tx = tid & 63;
        const int ty = tid >> 6;
#pragma unroll
        for (int r = 0; r < 16; ++r) {
            int k = ty + r * 4;
            t[k][tx] = ldf(W, (size_t)(k0 + k) * N + n0 + tx, f32);
        }
        __syncthreads();
#pragma unroll
        for (int r = 0; r < 16; ++r) {
            int n = ty + r * 4;
            WT[(size_t)(n0 + n) * K + k0 + tx] = __float2bfloat16(t[tx][n]);
        }
    } else {
        int y = b - 4640;           // 0..511
        int c = tid * 4;
        float s0 = 0, s1 = 0, s2 = 0, s3 = 0;
        float f0 = 0, f1 = 0, f2 = 0, f3 = 0;
        float l0 = 0, l1 = 0, l2 = 0, l3 = 0;
#pragma unroll
        for (int z = 0; z < C_; ++z) {
            size_t base = (size_t)(z * W_ + y) * 1024 + c;
            float a0, a1, a2, a3;
            if (f32) {
                float4 v = *(const float4*)((const float*)kv + base);
                a0 = v.x; a1 = v.y; a2 = v.z; a3 = v.w;
            } else {
                short4 v = *(const short4*)((const short*)kv + base);
                a0 = __bfloat162float(*(__hip_bfloat16*)&v.x);
                a1 = __bfloat162float(*(__hip_bfloat16*)&v.y);
                a2 = __bfloat162float(*(__hip_bfloat16*)&v.z);
                a3 = __bfloat162float(*(__hip_bfloat16*)&v.w);
            }
            s0 += a0; s1 += a1; s2 += a2; s3 += a3;
            if (z == 0) { f0 = a0; f1 = a1; f2 = a2; f3 = a3; }
            if (z == C_ - 1) { l0 = a0; l1 = a1; l2 = a2; l3 = a3; }
        }
        auto store = [&](int row, float x0, float x1, float x2, float x3) {
            __hip_bfloat162 tmp[2] = {__float22bfloat162_rn({x0, x1}),
                                      __float22bfloat162_rn({x2, x3})};
            *(short4*)((short*)kvcomb + (size_t)row * 1024 + c) = *(const short4*)tmp;
        };
        store(y,        s0 - l0, s1 - l1, s2 - l2, s3 - l3);
        store(512 + y,  s0, s1, s2, s3);
        store(1024 + y, s0 - f0, s1 - f1, s2 - f2, s3 - f3);
    }
}

// ---------------------------------------------------------------------------
// MFMA GEMM — R8 structure (128x64 tile, BK=64, 512-block grids, counted-
// vmcnt 2-phase). R9's 128x128 at 1 block/CU REGRESSED +8.6µs (m102/m132:
// lockstep 2-phase craters at 1 block/CU — do not re-try).
// cMode: 0 = follow flag, 1 = fp32, 2 = bf16, 3 = swizzled K/V epilogue.
// ntiles = N/64. Dual-problem dispatch: blocks [0,p0.nblocks) run p0.
// ---------------------------------------------------------------------------
struct GemmP {
    const __hip_bfloat16* A;
    const __hip_bfloat16* BT;
    void* C;
    int M, N, K;
    float alpha;
    int cMode;
    int ntiles;   // N / 64
    int swz;
    int nblocks;
    void* C2;
};

__global__ __launch_bounds__(256) void gemm_bt_mfma(GemmP p0, GemmP p1,
                                                    const int* __restrict__ flag) {
    __shared__ __hip_bfloat16 Asl[2][2][128 * 32];   // [buf][kc]
    __shared__ __hip_bfloat16 Bsl[2][2][64 * 32];

    GemmP p;
    int bid;
    if ((int)blockIdx.x < p0.nblocks) { p = p0; bid = blockIdx.x; }
    else { p = p1; bid = (int)blockIdx.x - p0.nblocks; }

    int mt, nt;
    if (!p.swz) { mt = bid / p.ntiles; nt = bid % p.ntiles; }
    else {
        int g = bid / (8 * p.ntiles);
        int rem = bid % (8 * p.ntiles);
        mt = g * 8 + (rem & 7);
        nt = rem >> 3;
    }
    const int m0 = mt * 128;
    const int n0 = nt * 64;
    const int K = p.K;
    const int N = p.N;

    const int tid = threadIdx.x;
    const int lane = tid & 63;
    const int wv = tid >> 6;
    const int wm = wv >> 1;
    const int wn = wv & 1;
    const int col = lane & 15;
    const int quad = lane >> 4;

    const int srow = lane >> 2;
    const int scol = (lane & 3) * 8;
    const __hip_bfloat16* Ag = p.A + (size_t)m0 * K;
    const __hip_bfloat16* Bg = p.BT + (size_t)n0 * K;

    f32x4 acc[4][2] = {};

    auto STAGE = [&](int bf, int k0) {   // 6 x async16 per thread
#pragma unroll
        for (int h = 0; h < 2; ++h) {
            int arow = wv * 32 + h * 16 + srow;
#pragma unroll
            for (int kc = 0; kc < 2; ++kc)
                async16(Ag + (size_t)arow * K + k0 + kc * 32 + scol,
                        &Asl[bf][kc][arow * 32 + scol]);
        }
        int brow = wv * 16 + srow;
#pragma unroll
        for (int kc = 0; kc < 2; ++kc)
            async16(Bg + (size_t)brow * K + k0 + kc * 32 + scol,
                    &Bsl[bf][kc][brow * 32 + scol]);
    };

    const int NT = K >> 6;
    STAGE(0, 0);                 // first iter's vmcnt(6) covers this

    int bf = 0;
    for (int t = 0; t < NT; ++t) {
        if (t + 1 < NT) {
            STAGE(bf ^ 1, (t + 1) << 6);   // 6 in flight across the barrier
            WAITV(6);                      // cur tile landed (mine)
        } else {
            WAITV(0);                      // peeled tail: drain
        }
        BARRIER();                          // all waves' cur loads landed

#pragma unroll
        for (int kc = 0; kc < 2; ++kc) {
            short8 af[4], bfr[2];
#pragma unroll
            for (int i = 0; i < 4; ++i)
                af[i] = *(const short8*)(&Asl[bf][kc][(wm * 64 + i * 16 + col) * 32 + quad * 8]);
#pragma unroll
            for (int j = 0; j < 2; ++j)
                bfr[j] = *(const short8*)(&Bsl[bf][kc][(wn * 32 + j * 16 + col) * 32 + quad * 8]);
#pragma unroll
            for (int am = 0; am < 4; ++am)
#pragma unroll
                for (int bn = 0; bn < 2; ++bn)
                    acc[am][bn] = __builtin_amdgcn_mfma_f32_16x16x32_bf16(af[am], bfr[bn], acc[am][bn], 0, 0, 0);
        }
        WAITL0();                           // my ds_reads of buf[bf] retired
        BARRIER();                          // safe to overwrite buf[bf] next iter
        bf ^= 1;
    }

    if (p.cMode == 3) {
        // K/V epilogue: scatter bf16 into swizzled tile images.
#pragma unroll
        for (int am = 0; am < 4; ++am)
#pragma unroll
            for (int bn = 0; bn < 2; ++bn)
#pragma unroll
                for (int r = 0; r < 4; ++r) {
                    int key = m0 + wm * 64 + am * 16 + quad * 4 + r;
                    int c = n0 + wn * 32 + bn * 16 + col;
                    float v = acc[am][bn][r];
                    int g = key >> 6, kr = key & 63;
                    if (c < 64) {
                        int byt = g * 8192 + kr * 128 +
                                  ((((c >> 3) ^ (kr & 7)) << 4)) + ((c & 7) << 1);
                        *(__hip_bfloat16*)((char*)p.C + byt) = __float2bfloat16(v);
                    } else {
                        int d = c - 64;
                        int pp = ((kr & 15) << 2) | (kr >> 4);
                        int byt = g * 8192 + d * 128 +
                                  ((((pp >> 3) ^ (d & 7)) << 4)) + ((pp & 7) << 1);
                        *(__hip_bfloat16*)((char*)p.C2 + byt) = __float2bfloat16(v);
                    }
                }
        return;
    }

    int cF = (p.cMode == 1) ? 1 : ((p.cMode == 2) ? 0 : flag[0]);
#pragma unroll
    for (int am = 0; am < 4; ++am)
#pragma unroll
        for (int bn = 0; bn < 2; ++bn)
#pragma unroll
            for (int r = 0; r < 4; ++r) {
                size_t ci = (size_t)(m0 + wm * 64 + am * 16 + quad * 4 + r) * N
                            + n0 + wn * 32 + bn * 16 + col;
                float v = acc[am][bn][r] * p.alpha;
                if (cF) ((float*)p.C)[ci] = v;
                else ((__hip_bfloat16*)p.C)[ci] = __float2bfloat16(v);
            }
}

// ---------------------------------------------------------------------------
// Flash MFMA attention — cross-tile QK pipeline (T15 analog). S (pre-exp2
// QK scores) carried across iterations: at iter t, exp2/pack/PV of tile t
// overlaps QK of tile t+1 (separate MFMA vs VALU/DS pipes, m114). 3-buffer
// rotation: stage(t+2) after barrier(t) overwrites slot(t-1) whose reads
// (kb at t-2, vb at t-1) completed before barrier(t). 32 q-rows/wave,
// swizzled K/V, wave-private P LDS, T5 setprio. VGPR ~120.
// ---------------------------------------------------------------------------
#define PSTRIDE 72
__global__ __launch_bounds__(256, 2) void attn_kernel(const __hip_bfloat16* __restrict__ qb,
                                                      const __hip_bfloat16* __restrict__ Kb,
                                                      const __hip_bfloat16* __restrict__ Vt,
                                                      __hip_bfloat16* __restrict__ ctx) {
    __shared__ __align__(16) __hip_bfloat16 Kbuf[3][4096];   // 3 x 8KB rotation
    __shared__ __align__(16) __hip_bfloat16 Vbuf[3][4096];   // 3 x 8KB rotation
    __shared__ __align__(16) __hip_bfloat16 psm[4][32 * PSTRIDE];

    const int tid = threadIdx.x;
    const int lane = tid & 63;
    const int wv = tid >> 6;
    const int m0 = blockIdx.x * 128 + wv * 32;   // this wave's 32 q-rows
    const int col = lane & 15;
    const int quad = lane >> 4;
    __hip_bfloat16* pw = psm[wv];

    const char* Kg = (const char*)Kb;
    const char* Vg = (const char*)Vt;
    const int so = tid * 16;                    // staging byte offset (linear)

    const int off0 = ((quad ^ (col & 7)) << 4);
    const int off1 = (((quad + 4) ^ (col & 7)) << 4);

    short8 qf[2][2];
#pragma unroll
    for (int rg = 0; rg < 2; ++rg) {
        const __hip_bfloat16* qp = qb + (size_t)(m0 + rg * 16 + col) * 64 + quad * 8;
        qf[rg][0] = *(const short8*)(qp);
        qf[rg][1] = *(const short8*)(qp + 32);
    }

    f32x4 O[2][4] = {};
    float lrow[2][4] = {};
    f32x4 S[2][4];               // carried: QK scores of tile t (pre-exp2)

    auto stage_tile = [&](int tile, int slot) {
        const char* ks = Kg + (size_t)tile * 8192;
        const char* vs = Vg + (size_t)tile * 8192;
        char* kd = (char*)Kbuf[slot];
        char* vd = (char*)Vbuf[slot];
        async16(ks + so, kd + so);
        async16(ks + 4096 + so, kd + 4096 + so);
        async16(vs + so, vd + so);
        async16(vs + 4096 + so, vd + 4096 + so);
    };

    auto qk_into = [&](const char* Kc, f32x4 (&Sd)[2][4]) {
        short8 kb0[4], kb1[4];
#pragma unroll
        for (int f = 0; f < 4; ++f) {
            const int rb = (f * 16 + col) * 128;
            kb0[f] = *(const short8*)(Kc + rb + off0);
            kb1[f] = *(const short8*)(Kc + rb + off1);
        }
        __builtin_amdgcn_s_setprio(1);
#pragma unroll
        for (int rg = 0; rg < 2; ++rg)
#pragma unroll
            for (int f = 0; f < 4; ++f) {
                f32x4 s = {};
                s = __builtin_amdgcn_mfma_f32_16x16x32_bf16(qf[rg][0], kb0[f], s, 0, 0, 0);
                s = __builtin_amdgcn_mfma_f32_16x16x32_bf16(qf[rg][1], kb1[f], s, 0, 0, 0);
                Sd[rg][f] = s;
            }
        __builtin_amdgcn_s_setprio(0);
    };

    // Prologue: stage tiles 0,1; QK(0) -> S.
    stage_tile(0, 0);
    stage_tile(1, 1);
    WAITV(4);            // tile 0 resident (tile 1 stays in flight)
    BARRIER();
    qk_into((const char*)Kbuf[0], S);

    int cur = 0;         // slot of tile t
    for (int t = 0; t < 24; ++t) {
        const int nx1 = (cur == 2) ? 0 : cur + 1;       // slot of tile t+1
        const int nx2 = (nx1 == 2) ? 0 : nx1 + 1;       // slot of tile t+2

        WAITV(0);        // tile t+1's loads (issued >=1 iter ago) landed
        BARRIER();       // all waves finished iter t-1 reads of slot nx2's old tile

        if (t < 22) stage_tile(t + 2, nx2);

        // --- softmax finish of tile t (S holds QK(t)) ---
#pragma unroll
        for (int rg = 0; rg < 2; ++rg) {
#pragma unroll
            for (int f = 0; f < 4; ++f)
#pragma unroll
                for (int r = 0; r < 4; ++r) S[rg][f][r] = FEXP2(S[rg][f][r]);
#pragma unroll
            for (int r = 0; r < 4; ++r)
                lrow[rg][r] += (S[rg][0][r] + S[rg][1][r]) + (S[rg][2][r] + S[rg][3][r]);
#pragma unroll
            for (int r = 0; r < 4; ++r) {
                __hip_bfloat162 p01 = __float22bfloat162_rn({S[rg][0][r], S[rg][1][r]});
                __hip_bfloat162 p23 = __float22bfloat162_rn({S[rg][2][r], S[rg][3][r]});
                short4 t4;
                *(__hip_bfloat162*)(&t4.x) = p01;
                *(__hip_bfloat162*)(&t4.z) = p23;
                *(short4*)(pw + (rg * 16 + quad * 4 + r) * PSTRIDE + col * 4) = t4;
            }
        }

        // --- QK of tile t+1 (independent MFMA work; overlaps PV/softmax) ---
        f32x4 Snew[2][4];
        if (t < 23) qk_into((const char*)Kbuf[nx1], Snew);

        // --- PV of tile t ---
        const char* Vc = (const char*)Vbuf[cur];
        short8 vb0[4], vb1[4];
#pragma unroll
        for (int f = 0; f < 4; ++f) {
            const int rb = (f * 16 + col) * 128;
            vb0[f] = *(const short8*)(Vc + rb + off0);
            vb1[f] = *(const short8*)(Vc + rb + off1);
        }
#pragma unroll
        for (int rg = 0; rg < 2; ++rg) {
            short8 a0 = *(const short8*)(pw + (rg * 16 + col) * PSTRIDE + quad * 8);
            short8 a1 = *(const short8*)(pw + (rg * 16 + col) * PSTRIDE + 32 + quad * 8);
            __builtin_amdgcn_s_setprio(1);
#pragma unroll
            for (int f = 0; f < 4; ++f) {
                O[rg][f] = __builtin_amdgcn_mfma_f32_16x16x32_bf16(a0, vb0[f], O[rg][f], 0, 0, 0);
                O[rg][f] = __builtin_amdgcn_mfma_f32_16x16x32_bf16(a1, vb1[f], O[rg][f], 0, 0, 0);
            }
            __builtin_amdgcn_s_setprio(0);
        }

        if (t < 23) {
#pragma unroll
            for (int rg = 0; rg < 2; ++rg)
#pragma unroll
                for (int f = 0; f < 4; ++f) S[rg][f] = Snew[rg][f];
        }
        cur = nx1;
    }

    // Sum lrow across the 16 cols of each quad-group (keys mod 16).
#pragma unroll
    for (int msk = 1; msk <= 8; msk <<= 1)
#pragma unroll
        for (int rg = 0; rg < 2; ++rg)
#pragma unroll
            for (int r = 0; r < 4; ++r) lrow[rg][r] += __shfl_xor(lrow[rg][r], msk, 64);

    // Direct epilogue: O[rg][f][r] is ctx[row = m0 + rg*16 + quad*4 + r][dh = f*16 + col].
#pragma unroll
    for (int rg = 0; rg < 2; ++rg)
#pragma unroll
        for (int r = 0; r < 4; ++r) {
            float inv = 1.f / lrow[rg][r];
#pragma unroll
            for (int f = 0; f < 4; ++f)
                ctx[(size_t)(m0 + rg * 16 + quad * 4 + r) * 64 + f * 16 + col] =
                    __float2bfloat16(O[rg][f][r] * inv);
        }
}

// ---------------------------------------------------------------------------
// Launch: 4 dispatches — megaprep -> merged GEMM (qb + K/V direct) -> attn
// -> out GEMM. GEMM grids 128x64-tiled (R8): 536 / 512 blocks.
// ---------------------------------------------------------------------------
extern "C" void kernel_launch(void* const* d_in, const int* in_sizes, int n_in,
                              void* d_out, int out_size, void* d_ws, size_t ws_size,
                              hipStream_t stream) {
    const void* q   = d_in[0];
    const void* kv  = d_in[1];
    const void* Wq  = d_in[2];
    const void* Wkv = d_in[3];
    const void* Wc  = d_in[4];

    char* ws = (char*)d_ws;
    size_t off = 0;
    int* flag = (int*)(ws + off); off += 1024;
    __hip_bfloat16* qbuf   = (__hip_bfloat16*)(ws + off); off += (size_t)L_ * DM_ * 2;     // 8 MB
    __hip_bfloat16* WqT    = (__hip_bfloat16*)(ws + off); off += (size_t)DM_ * DM_ * 2;    // 2 MB
    __hip_bfloat16* WkvT   = (__hip_bfloat16*)(ws + off); off += (size_t)128 * DM_ * 2;    // 256 KB
    __hip_bfloat16* WcT    = (__hip_bfloat16*)(ws + off); off += (size_t)DM_ * DM_ * 2;    // 2 MB
    __hip_bfloat16* qb     = (__hip_bfloat16*)(ws + off); off += (size_t)L_ * DM_ * 2;     // 8 MB
    __hip_bfloat16* kvcomb = (__hip_bfloat16*)(ws + off); off += (size_t)1536 * 1024 * 2;  // 3 MB
    __hip_bfloat16* Kb     = (__hip_bfloat16*)(ws + off); off += (size_t)W3_ * 64 * 2;     // 192 KB
    __hip_bfloat16* Vt     = (__hip_bfloat16*)(ws + off); off += (size_t)64 * W3_ * 2;     // 192 KB
    __hip_bfloat16* ctxb   = (__hip_bfloat16*)(ws + off);                                  // 8 MB

    megaprep<<<5152, 256, 0, stream>>>(q, kv, Wq, Wkv, Wc,
                                       qbuf, WqT, WkvT, WcT, kvcomb, flag);

    // Merged dispatch: qb = (q @ Wq) * (1/8)*log2(e), bf16 (512 blocks) PLUS
    // {Kb,Vt} = kvcomb @ Wkv with swizzled K/V epilogue (24 blocks).
    {
        GemmP pq{qbuf, WqT, (void*)qb, L_, DM_, DM_,
                 0.125f * 1.44269504f, 2, 16, 1, 512, nullptr};
        GemmP pk{kvcomb, WkvT, (void*)Kb, 1536, 128, DM_,
                 1.0f, 3, 2, 0, 24, (void*)Vt};
        gemm_bt_mfma<<<536, 256, 0, stream>>>(pq, pk, flag);
    }
    attn_kernel<<<dim3(NROWS_ / 128), 256, 0, stream>>>(qb, Kb, Vt, ctxb);
    // out = ctx @ Wc, dtype per flag
    {
        GemmP pc{ctxb, WcT, d_out, L_, DM_, DM_, 1.0f, 0, 16, 1, 512, nullptr};
        GemmP pnull{};
        pnull.nblocks = 0;
        gemm_bt_mfma<<<512, 256, 0, stream>>>(pc, pnull, flag);
    }
}